// Round 1
// baseline (335.164 us; speedup 1.0000x reference)
//
#include <hip/hip_runtime.h>
#include <hip/hip_bf16.h>

// Problem constants (from reference)
constexpr int Bn  = 16384;   // batch
constexpr int Fn  = 39;      // features per row
constexpr int NUMn = 13;     // masked slots
constexpr int En  = 64;      // embedding dim
constexpr int FDn = 26000;   // per-feature vocab

// One wave (64 lanes) per batch row.
//  lane split: s = lane&15 -> element chunk (float4), g = lane>>4 -> feature subgroup
//  logit[b] = sum_f scale(b,f) * dot(emb[feat+f*FD], w) + 39*bias
__global__ __launch_bounds__(256) void fused_emb_logit(
    const int*   __restrict__ features,    // [B*F]
    const int*   __restrict__ mask,        // [B*NUM]
    const unsigned char* __restrict__ mask_apply, // [B*NUM] bool (1 byte)
    const float* __restrict__ mask_value,  // [B*NUM]
    const float* __restrict__ emb,         // [F*FD, E]
    const float* __restrict__ lin_w,       // [E]
    const float* __restrict__ lin_b,       // [1]
    float*       __restrict__ out)         // [B]
{
    const int lane = threadIdx.x & 63;
    const int row  = blockIdx.x * (blockDim.x >> 6) + (threadIdx.x >> 6);
    if (row >= Bn) return;

    const int s = lane & 15;   // element sub-chunk (4 floats)
    const int g = lane >> 4;   // feature subgroup 0..3

    // ---- per-lane feature id & scatter-multiply scale for f = lane (lanes 0..38)
    int   feat  = 0;
    float scale = 1.0f;
    if (lane < Fn) {
        feat = features[row * Fn + lane];
#pragma unroll
        for (int n = 0; n < NUMn; ++n) {
            const int   m  = mask[row * NUMn + n];
            const bool  ap = mask_apply[row * NUMn + n] != 0;
            const float mv = mask_value[row * NUMn + n];
            if (m == lane && ap) scale *= mv;   // duplicates compose (scatter-mul)
        }
    }

    // ---- gather + scaled accumulate: 4 features per iteration via float4 lanes
    float4 acc = make_float4(0.f, 0.f, 0.f, 0.f);
#pragma unroll
    for (int f0 = 0; f0 < Fn; f0 += 4) {
        const int f  = f0 + g;
        const int fc = (f < Fn) ? f : (Fn - 1);            // clamp tail for safe addr
        const int fi = __shfl(feat, fc, 64);
        const float scv = __shfl(scale, fc, 64);
        const float sc  = (f < Fn) ? scv : 0.0f;

        const int base = (fi + fc * FDn) * En + s * 4;     // < 2^27, int-safe
        const float4 v = *reinterpret_cast<const float4*>(emb + base);
        acc.x = fmaf(sc, v.x, acc.x);
        acc.y = fmaf(sc, v.y, acc.y);
        acc.z = fmaf(sc, v.z, acc.z);
        acc.w = fmaf(sc, v.w, acc.w);
    }

    // ---- dot with w (each lane owns elements s*4 .. s*4+3), then 64-lane reduce
    const float4 w4 = *reinterpret_cast<const float4*>(lin_w + s * 4);
    float v = acc.x * w4.x + acc.y * w4.y + acc.z * w4.z + acc.w * w4.w;
#pragma unroll
    for (int off = 32; off > 0; off >>= 1)
        v += __shfl_down(v, off, 64);

    if (lane == 0) {
        const float logit = v + (float)Fn * lin_b[0];
        out[row] = 1.0f / (1.0f + expf(-logit));
    }
}

extern "C" void kernel_launch(void* const* d_in, const int* in_sizes, int n_in,
                              void* d_out, int out_size, void* d_ws, size_t ws_size,
                              hipStream_t stream) {
    const int*   features   = (const int*)  d_in[0];
    const int*   mask       = (const int*)  d_in[1];
    const unsigned char* mask_apply = (const unsigned char*)d_in[2];
    const float* mask_value = (const float*)d_in[3];
    const float* emb        = (const float*)d_in[4];
    const float* lin_w      = (const float*)d_in[5];
    const float* lin_b      = (const float*)d_in[6];
    float*       out        = (float*)d_out;

    // one wave per row: 4 waves/block -> B/4 blocks
    const int threads = 256;
    const int blocks  = Bn / (threads / 64);   // 4096
    fused_emb_logit<<<blocks, threads, 0, stream>>>(
        features, mask, mask_apply, mask_value, emb, lin_w, lin_b, out);
}